// Round 2
// baseline (1673.960 us; speedup 1.0000x reference)
//
#include <hip/hip_runtime.h>

#define BLOCK 256
#define NPB 64          // nodes per block (one per lane; 4 waves split columns)
#define NF 8            // node features
#define NE 32           // embed dim
#define NI 40           // F + E
#define NH 64           // hidden
#define SIN_W 44        // input row stride: 11 float4 (odd 16B stride -> conflict-free b128)
#define SH_W 68         // hidden row stride: 17 float4 (odd 16B stride -> conflict-free b128)

typedef float fvec16 __attribute__((ext_vector_type(16)));
typedef float fvec8  __attribute__((ext_vector_type(8)));

// Pre-pass: per main-kernel block, binary-search the segment containing its first node.
__global__ void seg_starts(const int* __restrict__ ptr, int* __restrict__ blockseg,
                           int nb, int n, int m)
{
    int b = blockIdx.x * blockDim.x + threadIdx.x;
    if (b >= nb) return;
    long long n0 = (long long)b * NPB;
    int node0 = (int)(n0 < n ? n0 : (long long)(n - 1));
    int lo = 0, hi = m;
    while (hi - lo > 1) {
        int mid = (lo + hi) >> 1;
        if (ptr[mid] <= node0) lo = mid; else hi = mid;
    }
    blockseg[b] = lo;
}

template<bool PRESEG>
__global__ __launch_bounds__(BLOCK, 4) void dag_mlp_seg(
    const float* __restrict__ x, const float* __restrict__ h_node,
    const float* __restrict__ W1, const float* __restrict__ b1,
    const float* __restrict__ W2, const float* __restrict__ b2,
    const float* __restrict__ W3, const float* __restrict__ b3,
    const int* __restrict__ ptr, float* __restrict__ out,
    const int* __restrict__ blockseg, int n, int m)
{
    // sIn: input rows [x(8)|h_node(32)], 64 x 44 floats = 11.3 KB
    // sH : hidden rows (H1, then reused for H2), 64 x 68 floats = 17.4 KB
    // total 28.7 KB -> 5 blocks/CU
    __shared__ float sIn[NPB * SIN_W];
    __shared__ float sH[NPB * SH_W];

    const int tid = threadIdx.x;
    const int nd  = tid & 63;                                   // node-in-block = lane
    const int g   = __builtin_amdgcn_readfirstlane(tid >> 6);   // wave = column group
    const long long node0 = (long long)blockIdx.x * NPB;
    const long long node  = node0 + nd;
    const bool valid = node < n;
    const int nodeC = (int)(valid ? node : (long long)(n - 1)); // clamped (outputs guarded)

    // ---- stage inputs into sIn rows (coalesced float4 global loads) ----
    {
        const long long x4max = ((long long)n * NF) / 4 - 1;
        const long long h4max = ((long long)n * NE) / 4 - 1;
        if (tid < 128) {                      // x: 64 nodes * 2 float4
            long long gi = node0 * (NF / 4) + tid;
            if (gi > x4max) gi = x4max;       // tail clamp (outputs guarded later)
            float4 v = reinterpret_cast<const float4*>(x)[gi];
            const int nd2 = tid >> 1, c = (tid & 1) * 4;
            *reinterpret_cast<float4*>(&sIn[nd2 * SIN_W + c]) = v;
        }
#pragma unroll
        for (int r = 0; r < 2; ++r) {         // h_node: 64 nodes * 8 float4
            const int j = tid + r * BLOCK;
            long long gi = node0 * (NE / 4) + j;
            if (gi > h4max) gi = h4max;
            float4 v = reinterpret_cast<const float4*>(h_node)[gi];
            const int nd2 = j >> 3, c = (j & 7) * 4;
            *reinterpret_cast<float4*>(&sIn[nd2 * SIN_W + NF + c]) = v;
        }
    }
    __syncthreads();

    float acc[16];

    // ---- layer 1: [40] -> [64]; wave g computes cols g*16..g*16+15 ----
    // activations consumed as float4 chunks (1 ds_read_b128 per 4 k-steps);
    // weights are wave-uniform -> s_load_dwordx16. Max live array = acc[16].
    {
        fvec16 bv = *reinterpret_cast<const fvec16*>(b1 + g * 16);
#pragma unroll
        for (int c = 0; c < 16; ++c) acc[c] = bv[c];
        const float4* aRow = reinterpret_cast<const float4*>(&sIn[nd * SIN_W]);
#pragma unroll
        for (int cb = 0; cb < NI / 4; ++cb) {
            const float4 a = aRow[cb];
            const float av[4] = { a.x, a.y, a.z, a.w };
#pragma unroll
            for (int kk = 0; kk < 4; ++kk) {
                fvec16 w = *reinterpret_cast<const fvec16*>(W1 + (cb * 4 + kk) * NH + g * 16);
#pragma unroll
                for (int c = 0; c < 16; ++c) acc[c] = fmaf(av[kk], w[c], acc[c]);
            }
        }
        float* o = &sH[nd * SH_W + g * 16];
#pragma unroll
        for (int i = 0; i < 4; ++i) {
            float4 v = { fmaxf(acc[i*4+0], 0.f), fmaxf(acc[i*4+1], 0.f),
                         fmaxf(acc[i*4+2], 0.f), fmaxf(acc[i*4+3], 0.f) };
            *reinterpret_cast<float4*>(o + i * 4) = v;
        }
    }
    __syncthreads();

    // ---- layer 2: [64] -> [64]; reads H1 chunks from sH ----
    {
        fvec16 bv = *reinterpret_cast<const fvec16*>(b2 + g * 16);
#pragma unroll
        for (int c = 0; c < 16; ++c) acc[c] = bv[c];
        const float4* aRow = reinterpret_cast<const float4*>(&sH[nd * SH_W]);
#pragma unroll
        for (int cb = 0; cb < NH / 4; ++cb) {
            const float4 a = aRow[cb];
            const float av[4] = { a.x, a.y, a.z, a.w };
#pragma unroll
            for (int kk = 0; kk < 4; ++kk) {
                fvec16 w = *reinterpret_cast<const fvec16*>(W2 + (cb * 4 + kk) * NH + g * 16);
#pragma unroll
                for (int c = 0; c < 16; ++c) acc[c] = fmaf(av[kk], w[c], acc[c]);
            }
        }
    }
    __syncthreads();      // all H1 reads done before rows are overwritten with H2
    {
        float* o = &sH[nd * SH_W + g * 16];
#pragma unroll
        for (int i = 0; i < 4; ++i) {
            float4 v = { fmaxf(acc[i*4+0], 0.f), fmaxf(acc[i*4+1], 0.f),
                         fmaxf(acc[i*4+2], 0.f), fmaxf(acc[i*4+3], 0.f) };
            *reinterpret_cast<float4*>(o + i * 4) = v;
        }
    }
    __syncthreads();

    // ---- layer 3: [64] -> [32]; wave g computes cols g*8..g*8+7 ----
    float ov[8];
    {
        fvec8 bv = *reinterpret_cast<const fvec8*>(b3 + g * 8);
#pragma unroll
        for (int c = 0; c < 8; ++c) ov[c] = bv[c];
        const float4* aRow = reinterpret_cast<const float4*>(&sH[nd * SH_W]);
#pragma unroll
        for (int cb = 0; cb < NH / 4; ++cb) {
            const float4 a = aRow[cb];
            const float av[4] = { a.x, a.y, a.z, a.w };
#pragma unroll
            for (int kk = 0; kk < 4; ++kk) {
                fvec8 w = *reinterpret_cast<const fvec8*>(W3 + (cb * 4 + kk) * NE + g * 8);
#pragma unroll
                for (int c = 0; c < 8; ++c) ov[c] = fmaf(av[kk], w[c], ov[c]);
            }
        }
    }

    // ---- segment id: block-level start (precomputed) + short per-lane scan ----
    int seg;
    if constexpr (PRESEG) {
        seg = blockseg[blockIdx.x];
    } else {
        const int node0C = (int)(node0 < n ? node0 : (long long)(n - 1));
        int lo = 0, hi = m;
        while (hi - lo > 1) {                 // wave-uniform scalar chain
            int mid = (lo + hi) >> 1;
            if (ptr[mid] <= node0C) lo = mid; else hi = mid;
        }
        seg = lo;
    }
    // advance to largest seg with ptr[seg] <= nodeC (avg <1 trip; ptr line L1-hot)
    while (seg + 1 < m && ptr[seg + 1] <= nodeC) ++seg;

    // ---- wave-level segmented suffix reduction; lanes = consecutive nodes ----
    const int lane = nd;
    const int segUp = __shfl_up(seg, 1);
    const bool head = (lane == 0) || (segUp != seg);

    bool take[6];
#pragma unroll
    for (int i = 0; i < 6; ++i) {
        const int d = 1 << i;
        const int s2 = __shfl_down(seg, d);
        take[i] = (lane + d < 64) && (s2 == seg);
    }

#pragma unroll
    for (int j = 0; j < 8; ++j) {
        float v = valid ? ov[j] : 0.f;
#pragma unroll
        for (int i = 0; i < 6; ++i) {
            const float w = __shfl_down(v, 1 << i);
            if (take[i]) v += w;
        }
        if (head && valid) {
            atomicAdd(&out[(size_t)seg * NE + g * 8 + j], v);
        }
    }
}

extern "C" void kernel_launch(void* const* d_in, const int* in_sizes, int n_in,
                              void* d_out, int out_size, void* d_ws, size_t ws_size,
                              hipStream_t stream) {
    const float* x      = (const float*)d_in[0];
    const float* h_node = (const float*)d_in[1];
    const float* W1     = (const float*)d_in[2];
    const float* b1     = (const float*)d_in[3];
    const float* W2     = (const float*)d_in[4];
    const float* b2     = (const float*)d_in[5];
    const float* W3     = (const float*)d_in[6];
    const float* b3     = (const float*)d_in[7];
    const int*   ptr    = (const int*)d_in[8];
    float* out = (float*)d_out;

    const int n = in_sizes[0] / NF;   // 2,000,000 nodes
    const int m = out_size / NE;      // 20,000 segments

    // out is accumulated with atomics; harness poisons it with 0xAA.
    hipMemsetAsync(d_out, 0, (size_t)out_size * sizeof(float), stream);

    const int nb = (n + NPB - 1) / NPB;
    const bool preseg = (d_ws != nullptr) && (ws_size >= (size_t)nb * sizeof(int));

    if (preseg) {
        int* blockseg = (int*)d_ws;
        seg_starts<<<(nb + 255) / 256, 256, 0, stream>>>(ptr, blockseg, nb, n, m);
        dag_mlp_seg<true><<<nb, BLOCK, 0, stream>>>(x, h_node, W1, b1, W2, b2, W3, b3,
                                                    ptr, out, blockseg, n, m);
    } else {
        dag_mlp_seg<false><<<nb, BLOCK, 0, stream>>>(x, h_node, W1, b1, W2, b2, W3, b3,
                                                     ptr, out, nullptr, n, m);
    }
}

// Round 3
// 822.217 us; speedup vs baseline: 2.0359x; 2.0359x over previous
//
#include <hip/hip_runtime.h>

#define BLOCK 256
#define NPB 64          // nodes per block (one per lane; 4 waves split columns)
#define NF 8            // node features
#define NE 32           // embed dim
#define NI 40           // F + E
#define NH 64           // hidden
#define LDSW 65         // LDS row stride (65 -> lane=node access is conflict-free)

typedef float fvec16 __attribute__((ext_vector_type(16)));
typedef float fvec8  __attribute__((ext_vector_type(8)));

__global__ __launch_bounds__(BLOCK, 4) void dag_mlp_seg(
    const float* __restrict__ x, const float* __restrict__ h_node,
    const float* __restrict__ W1, const float* __restrict__ b1,
    const float* __restrict__ W2, const float* __restrict__ b2,
    const float* __restrict__ W3, const float* __restrict__ b3,
    const int* __restrict__ ptr, float* __restrict__ out,
    int n, int m)
{
    // sA: inputs (rows of 40), later reused for H2 (rows of 64).
    // sB: H1 (rows of 64).  2 x 16.6 KB = 33.3 KB -> 4 blocks/CU.
    __shared__ float sA[NPB * LDSW];
    __shared__ float sB[NPB * LDSW];

    const int tid = threadIdx.x;
    const int nd  = tid & 63;                                   // node-in-block = lane
    // wave id; readfirstlane makes it provably uniform so weight-row loads
    // become s_load_dwordx16 (SGPRs), not per-lane vector loads.
    const int g   = __builtin_amdgcn_readfirstlane(tid >> 6);   // 0..3
    const long long node0 = (long long)blockIdx.x * NPB;

    // ---- stage inputs into sA rows: [x(8) | h_node(32)] ----
    {
        // x: 64 nodes * 8 floats = 128 float4
        const long long x4max  = ((long long)n * NF) / 4 - 1;
        const long long h4max  = ((long long)n * NE) / 4 - 1;
        if (tid < 128) {
            long long gi = node0 * (NF / 4) + tid;
            if (gi > x4max) gi = x4max;          // tail clamp (outputs guarded later)
            float4 v = reinterpret_cast<const float4*>(x)[gi];
            const int nd2 = tid >> 1, c = (tid & 1) * 4;
            float* p = &sA[nd2 * LDSW + c];
            p[0] = v.x; p[1] = v.y; p[2] = v.z; p[3] = v.w;
        }
        // h_node: 64 nodes * 32 floats = 512 float4, 2 per thread
#pragma unroll
        for (int r = 0; r < 2; ++r) {
            const int j = tid + r * BLOCK;       // 0..511
            long long gi = node0 * (NE / 4) + j;
            if (gi > h4max) gi = h4max;
            float4 v = reinterpret_cast<const float4*>(h_node)[gi];
            const int nd2 = j >> 3, c = (j & 7) * 4;
            float* p = &sA[nd2 * LDSW + NF + c];
            p[0] = v.x; p[1] = v.y; p[2] = v.z; p[3] = v.w;
        }
    }
    __syncthreads();

    // ---- layer 1: [40] -> [64], this wave computes cols g*16..g*16+15 ----
    float acc[16];
    {
        fvec16 bv = *reinterpret_cast<const fvec16*>(b1 + g * 16);
#pragma unroll
        for (int c = 0; c < 16; ++c) acc[c] = bv[c];
        const float* inRow = &sA[nd * LDSW];
#pragma unroll 8
        for (int k = 0; k < NI; ++k) {
            const float s = inRow[k];                                   // ds_read_b32
            fvec16 w = *reinterpret_cast<const fvec16*>(W1 + k * NH + g * 16); // s_load x16
#pragma unroll
            for (int c = 0; c < 16; ++c) acc[c] = fmaf(s, w[c], acc[c]);
        }
        float* o = &sB[nd * LDSW + g * 16];
#pragma unroll
        for (int c = 0; c < 16; ++c) o[c] = fmaxf(acc[c], 0.f);
    }
    __syncthreads();

    // ---- layer 2: [64] -> [64], reads sB (H1), writes sA (H2) ----
    {
        fvec16 bv = *reinterpret_cast<const fvec16*>(b2 + g * 16);
#pragma unroll
        for (int c = 0; c < 16; ++c) acc[c] = bv[c];
        const float* inRow = &sB[nd * LDSW];
#pragma unroll 8
        for (int k = 0; k < NH; ++k) {
            const float s = inRow[k];
            fvec16 w = *reinterpret_cast<const fvec16*>(W2 + k * NH + g * 16);
#pragma unroll
            for (int c = 0; c < 16; ++c) acc[c] = fmaf(s, w[c], acc[c]);
        }
        float* o = &sA[nd * LDSW + g * 16];
#pragma unroll
        for (int c = 0; c < 16; ++c) o[c] = fmaxf(acc[c], 0.f);
    }
    __syncthreads();

    // ---- layer 3: [64] -> [32], this wave computes cols g*8..g*8+7 ----
    float ov[8];
    {
        fvec8 bv = *reinterpret_cast<const fvec8*>(b3 + g * 8);
#pragma unroll
        for (int c = 0; c < 8; ++c) ov[c] = bv[c];
        const float* inRow = &sA[nd * LDSW];
#pragma unroll 8
        for (int k = 0; k < NH; ++k) {
            const float s = inRow[k];
            fvec8 w = *reinterpret_cast<const fvec8*>(W3 + k * NE + g * 8);
#pragma unroll
            for (int c = 0; c < 8; ++c) ov[c] = fmaf(s, w[c], ov[c]);
        }
    }

    // ---- segment id: largest seg with ptr[seg] <= node ----
    const long long node = node0 + nd;
    const bool valid = node < n;
    int seg = -1;
    if (valid) {
        int lo = 0, hi = m;
        while (hi - lo > 1) {
            int mid = (lo + hi) >> 1;
            if (ptr[mid] <= (int)node) lo = mid; else hi = mid;
        }
        seg = lo;
    }

    // ---- wave-level segmented suffix reduction; lanes = consecutive nodes ----
    const int lane = nd;
    const int segUp = __shfl_up(seg, 1);
    const bool head = (lane == 0) || (segUp != seg);

    bool take[6];
#pragma unroll
    for (int i = 0; i < 6; ++i) {
        const int d = 1 << i;
        const int s2 = __shfl_down(seg, d);
        take[i] = (lane + d < 64) && (s2 == seg);
    }

#pragma unroll
    for (int j = 0; j < 8; ++j) {
        float v = valid ? ov[j] : 0.f;
#pragma unroll
        for (int i = 0; i < 6; ++i) {
            const float w = __shfl_down(v, 1 << i);
            if (take[i]) v += w;
        }
        if (head && seg >= 0) {
            atomicAdd(&out[(size_t)seg * NE + g * 8 + j], v);
        }
    }
}

extern "C" void kernel_launch(void* const* d_in, const int* in_sizes, int n_in,
                              void* d_out, int out_size, void* d_ws, size_t ws_size,
                              hipStream_t stream) {
    const float* x      = (const float*)d_in[0];
    const float* h_node = (const float*)d_in[1];
    const float* W1     = (const float*)d_in[2];
    const float* b1     = (const float*)d_in[3];
    const float* W2     = (const float*)d_in[4];
    const float* b2     = (const float*)d_in[5];
    const float* W3     = (const float*)d_in[6];
    const float* b3     = (const float*)d_in[7];
    const int*   ptr    = (const int*)d_in[8];
    float* out = (float*)d_out;

    const int n = in_sizes[0] / NF;   // 2,000,000 nodes
    const int m = out_size / NE;      // 20,000 segments

    // out is accumulated with atomics; harness poisons it with 0xAA.
    hipMemsetAsync(d_out, 0, (size_t)out_size * sizeof(float), stream);

    const int nb = (n + NPB - 1) / NPB;
    dag_mlp_seg<<<nb, BLOCK, 0, stream>>>(x, h_node, W1, b1, W2, b2, W3, b3,
                                          ptr, out, n, m);
}

// Round 4
// 719.361 us; speedup vs baseline: 2.3270x; 1.1430x over previous
//
#include <hip/hip_runtime.h>

#define BLOCK 256
#define NPB 64          // nodes per block (one per lane; 4 waves split columns)
#define NF 8            // node features
#define NE 32           // embed dim
#define NI 40           // F + E
#define NH 64           // hidden
#define SA_W 41         // input row stride (40+1; odd -> lane=node access 2-way max)
#define SB_W 65         // hidden row stride (64+1; odd -> conflict-free)

typedef float fvec16 __attribute__((ext_vector_type(16)));
typedef float fvec8  __attribute__((ext_vector_type(8)));

// Pre-pass: per main-kernel block, binary-search the segment containing its first node.
__global__ void seg_starts(const int* __restrict__ ptr, int* __restrict__ blockseg,
                           int nb, int n, int m)
{
    int b = blockIdx.x * blockDim.x + threadIdx.x;
    if (b >= nb) return;
    long long n0 = (long long)b * NPB;
    int node0 = (int)(n0 < n ? n0 : (long long)(n - 1));
    int lo = 0, hi = m;
    while (hi - lo > 1) {
        int mid = (lo + hi) >> 1;
        if (ptr[mid] <= node0) lo = mid; else hi = mid;
    }
    blockseg[b] = lo;
}

template<bool PRESEG>
__global__ __launch_bounds__(BLOCK, 6) void dag_mlp_seg(
    const float* __restrict__ x, const float* __restrict__ h_node,
    const float* __restrict__ W1, const float* __restrict__ b1,
    const float* __restrict__ W2, const float* __restrict__ b2,
    const float* __restrict__ W3, const float* __restrict__ b3,
    const int* __restrict__ ptr, float* __restrict__ out,
    const int* __restrict__ blockseg, int n, int m)
{
    // sA: input rows [x(8)|h_node(32)], 64 x 41 = 10.5 KB
    // sB: H1 rows, then (after an extra barrier) H2 rows, 64 x 65 = 16.6 KB
    // total 27,136 B -> 6 blocks/CU (6 x 27,136 = 162,816 <= 163,840)
    __shared__ float sA[NPB * SA_W];
    __shared__ float sB[NPB * SB_W];

    const int tid = threadIdx.x;
    const int nd  = tid & 63;                                   // node-in-block = lane
    // wave id; readfirstlane makes it provably uniform so weight-row loads
    // become s_load_dwordx16 (SGPRs), not per-lane vector loads.
    const int g   = __builtin_amdgcn_readfirstlane(tid >> 6);   // 0..3
    const long long node0 = (long long)blockIdx.x * NPB;

    // ---- stage inputs into sA rows: [x(8) | h_node(32)] ----
    {
        // x: 64 nodes * 8 floats = 128 float4
        const long long x4max  = ((long long)n * NF) / 4 - 1;
        const long long h4max  = ((long long)n * NE) / 4 - 1;
        if (tid < 128) {
            long long gi = node0 * (NF / 4) + tid;
            if (gi > x4max) gi = x4max;          // tail clamp (outputs guarded later)
            float4 v = reinterpret_cast<const float4*>(x)[gi];
            const int nd2 = tid >> 1, c = (tid & 1) * 4;
            float* p = &sA[nd2 * SA_W + c];
            p[0] = v.x; p[1] = v.y; p[2] = v.z; p[3] = v.w;
        }
        // h_node: 64 nodes * 32 floats = 512 float4, 2 per thread
#pragma unroll
        for (int r = 0; r < 2; ++r) {
            const int j = tid + r * BLOCK;       // 0..511
            long long gi = node0 * (NE / 4) + j;
            if (gi > h4max) gi = h4max;
            float4 v = reinterpret_cast<const float4*>(h_node)[gi];
            const int nd2 = j >> 3, c = (j & 7) * 4;
            float* p = &sA[nd2 * SA_W + NF + c];
            p[0] = v.x; p[1] = v.y; p[2] = v.z; p[3] = v.w;
        }
    }
    __syncthreads();

    // ---- layer 1: [40] -> [64], this wave computes cols g*16..g*16+15 ----
    float acc[16];
    {
        fvec16 bv = *reinterpret_cast<const fvec16*>(b1 + g * 16);
#pragma unroll
        for (int c = 0; c < 16; ++c) acc[c] = bv[c];
        const float* inRow = &sA[nd * SA_W];
#pragma unroll 8
        for (int k = 0; k < NI; ++k) {
            const float s = inRow[k];                                   // ds_read_b32
            fvec16 w = *reinterpret_cast<const fvec16*>(W1 + k * NH + g * 16); // s_load x16
#pragma unroll
            for (int c = 0; c < 16; ++c) acc[c] = fmaf(s, w[c], acc[c]);
        }
        float* o = &sB[nd * SB_W + g * 16];
#pragma unroll
        for (int c = 0; c < 16; ++c) o[c] = fmaxf(acc[c], 0.f);
    }
    __syncthreads();

    // ---- layer 2: [64] -> [64], reads sB (H1); H2 overwrites sB after a barrier ----
    {
        fvec16 bv = *reinterpret_cast<const fvec16*>(b2 + g * 16);
#pragma unroll
        for (int c = 0; c < 16; ++c) acc[c] = bv[c];
        const float* inRow = &sB[nd * SB_W];
#pragma unroll 8
        for (int k = 0; k < NH; ++k) {
            const float s = inRow[k];
            fvec16 w = *reinterpret_cast<const fvec16*>(W2 + k * NH + g * 16);
#pragma unroll
            for (int c = 0; c < 16; ++c) acc[c] = fmaf(s, w[c], acc[c]);
        }
    }
    __syncthreads();       // all H1 reads complete before anyone overwrites sB
    {
        float* o = &sB[nd * SB_W + g * 16];
#pragma unroll
        for (int c = 0; c < 16; ++c) o[c] = fmaxf(acc[c], 0.f);
    }
    __syncthreads();

    // ---- layer 3: [64] -> [32], this wave computes cols g*8..g*8+7 ----
    float ov[8];
    {
        fvec8 bv = *reinterpret_cast<const fvec8*>(b3 + g * 8);
#pragma unroll
        for (int c = 0; c < 8; ++c) ov[c] = bv[c];
        const float* inRow = &sB[nd * SB_W];
#pragma unroll 8
        for (int k = 0; k < NH; ++k) {
            const float s = inRow[k];
            fvec8 w = *reinterpret_cast<const fvec8*>(W3 + k * NE + g * 8);
#pragma unroll
            for (int c = 0; c < 8; ++c) ov[c] = fmaf(s, w[c], ov[c]);
        }
    }

    // ---- segment id ----
    const long long node = node0 + nd;
    const bool valid = node < n;
    const int nodeC = (int)(valid ? node : (long long)(n - 1));
    int seg;
    if constexpr (PRESEG) {
        seg = blockseg[blockIdx.x];          // 1 load (L2-hot)
    } else {
        // wave-uniform binary search on the block's first node
        const int node0C = (int)(node0 < n ? node0 : (long long)(n - 1));
        int lo = 0, hi = m;
        while (hi - lo > 1) {
            int mid = (lo + hi) >> 1;
            if (ptr[mid] <= node0C) lo = mid; else hi = mid;
        }
        seg = lo;
    }
    // advance to largest seg with ptr[seg] <= nodeC (avg ~0.64 trips/block; L1-hot)
    while (seg + 1 < m && ptr[seg + 1] <= nodeC) ++seg;

    // ---- wave-level segmented suffix reduction; lanes = consecutive nodes ----
    const int lane = nd;
    const int segUp = __shfl_up(seg, 1);
    const bool head = (lane == 0) || (segUp != seg);

    bool take[6];
#pragma unroll
    for (int i = 0; i < 6; ++i) {
        const int d = 1 << i;
        const int s2 = __shfl_down(seg, d);
        take[i] = (lane + d < 64) && (s2 == seg);
    }

#pragma unroll
    for (int j = 0; j < 8; ++j) {
        float v = valid ? ov[j] : 0.f;
#pragma unroll
        for (int i = 0; i < 6; ++i) {
            const float w = __shfl_down(v, 1 << i);
            if (take[i]) v += w;
        }
        if (head && valid) {
            atomicAdd(&out[(size_t)seg * NE + g * 8 + j], v);
        }
    }
}

extern "C" void kernel_launch(void* const* d_in, const int* in_sizes, int n_in,
                              void* d_out, int out_size, void* d_ws, size_t ws_size,
                              hipStream_t stream) {
    const float* x      = (const float*)d_in[0];
    const float* h_node = (const float*)d_in[1];
    const float* W1     = (const float*)d_in[2];
    const float* b1     = (const float*)d_in[3];
    const float* W2     = (const float*)d_in[4];
    const float* b2     = (const float*)d_in[5];
    const float* W3     = (const float*)d_in[6];
    const float* b3     = (const float*)d_in[7];
    const int*   ptr    = (const int*)d_in[8];
    float* out = (float*)d_out;

    const int n = in_sizes[0] / NF;   // 2,000,000 nodes
    const int m = out_size / NE;      // 20,000 segments

    // out is accumulated with atomics; harness poisons it with 0xAA.
    hipMemsetAsync(d_out, 0, (size_t)out_size * sizeof(float), stream);

    const int nb = (n + NPB - 1) / NPB;
    const bool preseg = (d_ws != nullptr) && (ws_size >= (size_t)nb * sizeof(int));

    if (preseg) {
        int* blockseg = (int*)d_ws;
        seg_starts<<<(nb + 255) / 256, 256, 0, stream>>>(ptr, blockseg, nb, n, m);
        dag_mlp_seg<true><<<nb, BLOCK, 0, stream>>>(x, h_node, W1, b1, W2, b2, W3, b3,
                                                    ptr, out, blockseg, n, m);
    } else {
        dag_mlp_seg<false><<<nb, BLOCK, 0, stream>>>(x, h_node, W1, b1, W2, b2, W3, b3,
                                                     ptr, out, nullptr, n, m);
    }
}